// Round 8
// baseline (3293.074 us; speedup 1.0000x reference)
//
#include <hip/hip_runtime.h>

#define O_N 100000
#define R_N 1000000
#define DIM 128
#define SD 384
#define HD 256
#define BR 64
#define NT (R_N / BR)        // 15625 tiles
#define GRIDP 512            // persistent blocks: 2/CU x 256 CUs
#define OBJ8 (O_N * DIM / 8)
#define REL8 (R_N * DIM / 8)

typedef __attribute__((ext_vector_type(8))) short short8;
typedef __attribute__((ext_vector_type(4))) float f32x4;
typedef __attribute__((ext_vector_type(4))) int i32x4;

static __device__ __forceinline__ unsigned short f2bf(float x) {
    union { float f; unsigned int u; } v; v.f = x;
    unsigned int r = v.u + 0x7FFFu + ((v.u >> 16) & 1u);
    return (unsigned short)(r >> 16);
}
static __device__ __forceinline__ unsigned long long pack4(f32x4 v) {
    return  (unsigned long long)f2bf(v.x)
         | ((unsigned long long)f2bf(v.y) << 16)
         | ((unsigned long long)f2bf(v.z) << 32)
         | ((unsigned long long)f2bf(v.w) << 48);
}

// ---- K0: transpose + convert weights to bf16 ----------------------------
__global__ void prep_weights(const float* __restrict__ W1, const float* __restrict__ W2,
                             unsigned short* __restrict__ W1T, unsigned short* __restrict__ W2T) {
    int i = blockIdx.x * 256 + threadIdx.x;
    if (i < SD * HD) {                 // W1T[h][k] = W1[k][h]
        int h = i / SD, k = i - h * SD;
        W1T[i] = f2bf(W1[k * HD + h]);
    } else {
        int j = i - SD * HD;           // W2T[c][k] = W2[k][c]
        int c = j / HD, k = j - c * HD;
        W2T[j] = f2bf(W2[k * SD + c]);
    }
}

// ---- K1: pre-convert object_feats + relation_feats to bf16 ---------------
__global__ void conv_bf16(const float* __restrict__ objF, const float* __restrict__ relF,
                          unsigned short* __restrict__ objBF, unsigned short* __restrict__ relBF) {
    long long i = (long long)blockIdx.x * 256 + threadIdx.x;   // one 8-elt group
    if (i >= (long long)OBJ8 + REL8) return;
    const float* s; unsigned short* d;
    if (i < OBJ8) { s = objF + i * 8;           d = objBF + i * 8; }
    else          { long long j = i - OBJ8; s = relF + j * 8; d = relBF + j * 8; }
    f32x4 v0 = ((const f32x4*)s)[0];
    f32x4 v1 = ((const f32x4*)s)[1];
    unsigned long long* dd = (unsigned long long*)d;
    dd[0] = pack4(v0);
    dd[1] = pack4(v1);
}

// ---- K2: triplet copy + degree counts + clamped idx arrays ---------------
__global__ void trip_cnt(const int* __restrict__ trip, float* __restrict__ tripOut,
                         float* __restrict__ lenOut, float* __restrict__ cnt,
                         int* __restrict__ subIdx, int* __restrict__ objIdx,
                         const int* __restrict__ tlen) {
    int i = blockIdx.x * 256 + threadIdx.x;
    if (i < R_N) {
        int s = trip[3 * i], o = trip[3 * i + 1], t2 = trip[3 * i + 2];
        tripOut[3 * i]     = (float)s;
        tripOut[3 * i + 1] = (float)o;
        tripOut[3 * i + 2] = (float)t2;
        int sc = min(max(s, 0), O_N - 1);
        int oc = min(max(o, 0), O_N - 1);
        subIdx[i] = sc;
        objIdx[i] = oc;
        atomicAdd(&cnt[sc], 1.0f);
        atomicAdd(&cnt[oc], 1.0f);
        if (i == 0) lenOut[0] = (float)tlen[0];
    }
}

// ---- K3: persistent pipelined gather -> MLP -> scatter kernel -------------
// 512 blocks x ~30 tiles each. Per tile: GEMM1 | B1 | pack + issue-fill(t+1)
// | lgkm+B2 | GEMM2 | vmcnt(0)+B3 | epilogue (atomics drain at NEXT B3).
// Raw s_barrier (no compiler vmcnt(0) drain) keeps fills/atomics in flight
// across barriers. LDS = 48K Xs + 32K Hs = 81920 B exactly -> 2 blocks/CU.
__global__ __launch_bounds__(256, 2)
void mlp_kernel(const unsigned short* __restrict__ objBF, const unsigned short* __restrict__ relBF,
                const unsigned short* __restrict__ W1T, const unsigned short* __restrict__ W2T,
                const float* __restrict__ b1, const float* __restrict__ b2,
                const int* __restrict__ subIdx, const int* __restrict__ objIdx,
                float* __restrict__ accB, float* __restrict__ relOut) {
    __shared__ __align__(16) unsigned char Xs[49152];   // X[64][384] bf16, XOR-swizzled
    __shared__ __align__(16) unsigned char Hs[32768];   // H[64][256] bf16, XOR-swizzled

    const int tid  = threadIdx.x;
    const int lane = tid & 63;
    const int w    = tid >> 6;
    const int l15  = lane & 15;
    const int l4   = lane >> 4;
    const int hW   = w * 64;
    const int cW   = w * 96;

    // fill: 12 x 1KB segments per wave; stored unit p holds source unit
    // u = p ^ (row&15) (inverse swizzle on the GLOBAL side, linear LDS dest).
    #define FILL(TT)                                                          \
    {                                                                         \
        int rb_ = (TT) * BR;                                                  \
        _Pragma("unroll")                                                     \
        for (int j = 0; j < 12; ++j) {                                        \
            int seg = w * 12 + j;                                             \
            int a   = seg * 64 + lane;                                        \
            int row = a / 48;                                                 \
            int p   = a - row * 48;                                           \
            int u   = p ^ (row & 15);                                         \
            const unsigned short* src;                                        \
            if (u < 16)      src = objBF + (size_t)subIdx[rb_ + row] * DIM + u * 8;        \
            else if (u < 32) src = relBF + (size_t)(rb_ + row) * DIM + (u - 16) * 8;       \
            else             src = objBF + (size_t)objIdx[rb_ + row] * DIM + (u - 32) * 8; \
            __builtin_amdgcn_global_load_lds(                                 \
                (const __attribute__((address_space(1))) void*)src,           \
                (__attribute__((address_space(3))) void*)(Xs + seg * 1024),   \
                16, 0, 0);                                                    \
        }                                                                     \
    }

    int t = blockIdx.x;
    if (t < NT) FILL(t);
    asm volatile("s_waitcnt vmcnt(0)" ::: "memory");
    __builtin_amdgcn_s_barrier();
    __builtin_amdgcn_sched_barrier(0);

    for (; t < NT; t += GRIDP) {
        // ---- GEMM1 (swapped): D1[h][rel] = W1T(A) * X^T(B) --------------
        f32x4 acc1[4][4];
        #pragma unroll
        for (int a = 0; a < 4; ++a)
            #pragma unroll
            for (int b = 0; b < 4; ++b) acc1[a][b] = (f32x4)0.0f;

        #pragma unroll
        for (int ks = 0; ks < 12; ++ks) {
            int k0 = ks * 32;
            short8 af[4], bfr[4];
            #pragma unroll
            for (int mh = 0; mh < 4; ++mh) {
                int h = hW + mh * 16 + l15;
                af[mh] = *(const short8*)(W1T + h * SD + k0 + 8 * l4);
            }
            #pragma unroll
            for (int nr = 0; nr < 4; ++nr) {
                int rel = nr * 16 + l15;
                int kb  = (k0 >> 3) + l4;
                bfr[nr] = *(const short8*)(Xs + rel * 768 + ((kb ^ (rel & 15)) << 4));
            }
            #pragma unroll
            for (int mh = 0; mh < 4; ++mh)
                #pragma unroll
                for (int nr = 0; nr < 4; ++nr)
                    acc1[mh][nr] = __builtin_amdgcn_mfma_f32_16x16x32_bf16(
                        af[mh], bfr[nr], acc1[mh][nr], 0, 0, 0);
        }

        __builtin_amdgcn_s_barrier();              // B1: Xs fully consumed
        __builtin_amdgcn_sched_barrier(0);

        // ---- bias + relu + pack -> Hs; then issue next tile's fill ------
        #pragma unroll
        for (int mh = 0; mh < 4; ++mh) {
            int hbase = hW + mh * 16 + 4 * l4;
            float bb0 = b1[hbase], bb1 = b1[hbase + 1], bb2 = b1[hbase + 2], bb3 = b1[hbase + 3];
            int hb   = hbase >> 3;
            int half = (hbase >> 2) & 1;
            #pragma unroll
            for (int nr = 0; nr < 4; ++nr) {
                int rel = nr * 16 + l15;
                unsigned long long pk =
                      (unsigned long long)f2bf(fmaxf(acc1[mh][nr][0] + bb0, 0.f))
                    | ((unsigned long long)f2bf(fmaxf(acc1[mh][nr][1] + bb1, 0.f)) << 16)
                    | ((unsigned long long)f2bf(fmaxf(acc1[mh][nr][2] + bb2, 0.f)) << 32)
                    | ((unsigned long long)f2bf(fmaxf(acc1[mh][nr][3] + bb3, 0.f)) << 48);
                *(unsigned long long*)(Hs + rel * 512 + ((hb ^ (rel & 15)) << 4) + half * 8) = pk;
            }
        }
        {
            int tn = t + GRIDP;
            if (tn < NT) FILL(tn);                 // in flight under GEMM2
        }
        asm volatile("s_waitcnt lgkmcnt(0)" ::: "memory");
        __builtin_amdgcn_s_barrier();              // B2: Hs visible
        __builtin_amdgcn_sched_barrier(0);

        // ---- GEMM2: D2[rel][c] = H(A) * W2T(B) --------------------------
        f32x4 acc2[4][6];
        #pragma unroll
        for (int a = 0; a < 4; ++a)
            #pragma unroll
            for (int b = 0; b < 6; ++b) acc2[a][b] = (f32x4)0.0f;

        #pragma unroll
        for (int ks = 0; ks < 8; ++ks) {
            int k0 = ks * 32;
            short8 ha[4], wb[6];
            #pragma unroll
            for (int ma = 0; ma < 4; ++ma) {
                int rel = ma * 16 + l15;
                int hb  = (k0 >> 3) + l4;
                ha[ma] = *(const short8*)(Hs + rel * 512 + ((hb ^ (rel & 15)) << 4));
            }
            #pragma unroll
            for (int nb = 0; nb < 6; ++nb) {
                int c = cW + nb * 16 + l15;
                wb[nb] = *(const short8*)(W2T + c * HD + k0 + 8 * l4);
            }
            #pragma unroll
            for (int ma = 0; ma < 4; ++ma)
                #pragma unroll
                for (int nb = 0; nb < 6; ++nb)
                    acc2[ma][nb] = __builtin_amdgcn_mfma_f32_16x16x32_bf16(
                        ha[ma], wb[nb], acc2[ma][nb], 0, 0, 0);
        }

        asm volatile("s_waitcnt vmcnt(0)" ::: "memory");  // fills landed;
        __builtin_amdgcn_s_barrier();              // B3     prev atomics done
        __builtin_amdgcn_sched_barrier(0);

        // ---- epilogue(t): bias + region-split store / f32 scatter-add ---
        // Issued after B3 -> stays in flight until next tile's B3.
        {
            int r0t = t * BR;
            #pragma unroll
            for (int ma = 0; ma < 4; ++ma) {
                int rloc = ma * 16 + 4 * l4;
                int rg   = r0t + rloc;
                i32x4 sv = *(const i32x4*)(subIdx + rg);
                i32x4 ov = *(const i32x4*)(objIdx + rg);
                #pragma unroll
                for (int nb = 0; nb < 6; ++nb) {
                    int c = cW + nb * 16 + l15;
                    float b2v = b2[c];
                    #pragma unroll
                    for (int q = 0; q < 4; ++q) {
                        float v = acc2[ma][nb][q] + b2v;
                        if (c < DIM) {
                            atomicAdd(accB + (size_t)sv[q] * DIM + c, v);
                        } else if (c < 2 * DIM) {
                            relOut[(size_t)(rg + q) * DIM + (c - DIM)] = v;
                        } else {
                            atomicAdd(accB + (size_t)ov[q] * DIM + (c - 2 * DIM), v);
                        }
                    }
                }
            }
        }
    }
    #undef FILL
}

// ---- K4: output_feat = acc / max(cnt,1) + object_feats -------------------
__global__ void finalize(const float* __restrict__ accB, const float* __restrict__ cnt,
                         const float* __restrict__ objF, float* __restrict__ outF) {
    int i = blockIdx.x * 256 + threadIdx.x;      // float4 index
    if (i < O_N * DIM / 4) {
        int row = i >> 5;                        // DIM/4 = 32 float4 per row
        float c = fmaxf(cnt[row], 1.0f);
        f32x4 a = ((const f32x4*)accB)[i];
        f32x4 o = ((const f32x4*)objF)[i];
        f32x4 r;
        r.x = a.x / c + o.x;
        r.y = a.y / c + o.y;
        r.z = a.z / c + o.z;
        r.w = a.w / c + o.w;
        ((f32x4*)outF)[i] = r;
    }
}

extern "C" void kernel_launch(void* const* d_in, const int* in_sizes, int n_in,
                              void* d_out, int out_size, void* d_ws, size_t ws_size,
                              hipStream_t stream) {
    const float* objF = (const float*)d_in[0];
    const float* relF = (const float*)d_in[1];
    const float* W1   = (const float*)d_in[2];
    const float* b1   = (const float*)d_in[3];
    const float* W2   = (const float*)d_in[4];
    const float* b2   = (const float*)d_in[5];
    const int*   trip = (const int*)d_in[6];
    const int*   tlen = (const int*)d_in[7];

    float* outF    = (float*)d_out;
    float* relOut  = outF + (size_t)O_N * DIM;          // 12.8M
    float* tripOut = relOut + (size_t)R_N * DIM;        // +128M
    float* lenOut  = tripOut + (size_t)R_N * 3;         // +3M

    // ws layout (~342 MB): W | accB | cnt | objBF | relBF | subIdx | objIdx
    unsigned short* W1T = (unsigned short*)d_ws;
    unsigned short* W2T = W1T + SD * HD;
    float* accB = (float*)(W2T + SD * HD);
    float* cnt  = accB + (size_t)O_N * DIM;
    unsigned short* objBF = (unsigned short*)(cnt + O_N);
    unsigned short* relBF = objBF + (size_t)O_N * DIM;
    int* subIdx = (int*)(relBF + (size_t)R_N * DIM);
    int* objIdx = subIdx + R_N;

    (void)hipMemsetAsync(accB, 0, ((size_t)O_N * DIM + O_N) * sizeof(float), stream);
    prep_weights<<<(2 * SD * HD) / 256, 256, 0, stream>>>(W1, W2, W1T, W2T);
    conv_bf16<<<(OBJ8 + REL8 + 255) / 256, 256, 0, stream>>>(objF, relF, objBF, relBF);
    trip_cnt<<<(R_N + 255) / 256, 256, 0, stream>>>(trip, tripOut, lenOut, cnt, subIdx, objIdx, tlen);
    mlp_kernel<<<GRIDP, 256, 0, stream>>>(objBF, relBF, W1T, W2T, b1, b2, subIdx, objIdx, accB, relOut);
    finalize<<<(O_N * DIM / 4 + 255) / 256, 256, 0, stream>>>(accB, cnt, objF, outF);
}